// Round 1
// baseline (263.635 us; speedup 1.0000x reference)
//
#include <hip/hip_runtime.h>

typedef __bf16 bf16x8 __attribute__((ext_vector_type(8)));
typedef float f32x4 __attribute__((ext_vector_type(4)));
typedef unsigned int u32;
typedef unsigned short u16;

#define LOG2E 1.44269504088896f

__device__ __forceinline__ u16 f2bf(float f){
  u32 b = __builtin_bit_cast(u32, f);
  b += 0x7FFFu + ((b >> 16) & 1u);
  return (u16)(b >> 16);
}

// ---------------------------------------------------------------------------
// prep_w: build fragment-ordered bf16 weights.
// flat idx = ((cc*24+dt)*64 + lane)*8 + e  ->  W[d = dt*16+(lane&15)][c = cc*32+(lane>>4)*8+e]
// rows 0..63 = w_q, 64..127 = w_k, 128..383 = w_v
// ---------------------------------------------------------------------------
__global__ void prep_w(const float* __restrict__ wq, const float* __restrict__ wk,
                       const float* __restrict__ wv, u16* __restrict__ wfrag){
  int idx  = blockIdx.x * 256 + threadIdx.x;     // < 98304
  int e    = idx & 7;
  int lane = (idx >> 3) & 63;
  int f    = idx >> 9;                           // 0..191
  int cc = f / 24, dt = f % 24;
  int d = dt * 16 + (lane & 15);
  int c = cc * 32 + (lane >> 4) * 8 + e;
  float v;
  if (d < 64)       v = wq[d * 256 + c];
  else if (d < 128) v = wk[(d - 64) * 256 + c];
  else              v = wv[(d - 128) * 256 + c];
  wfrag[idx] = f2bf(v);
}

// ---------------------------------------------------------------------------
// proj_kernel: per (batch b, 64-column tile n0): Out[d][n] = sum_c W[d][c] x[b][c][n] + bias
//   writes Q,K as [B][N][64] bf16 (d contiguous), V as [B][256][N] bf16 (n contiguous)
// x tile transposed+converted into LDS [n][c] bf16, 512B rows, 16B-block XOR swizzle by (n&31).
// ---------------------------------------------------------------------------
__launch_bounds__(256, 2)
__global__ void proj_kernel(const float* __restrict__ x,
                            const float* __restrict__ bq, const float* __restrict__ bk,
                            const float* __restrict__ bv,
                            const u16* __restrict__ wfrag,
                            u16* __restrict__ qb, u16* __restrict__ kb, u16* __restrict__ vt)
{
  __shared__ u16 xlds[64 * 256];     // 32 KB
  const int b    = blockIdx.x & 7;
  const int n0   = (blockIdx.x >> 3) * 64;
  const int t    = threadIdx.x;
  const int lane = t & 63;
  const int w    = t >> 6;
  const int g    = lane >> 4, j = lane & 15;

  // ---- stage: transpose-convert x[b][:, n0..n0+63] into xlds[n][c] ----
  {
    const int n = t & 63;
    const float* xp = x + ((size_t)b * 256) * 4096 + n0 + n;
    char* lbase = reinterpret_cast<char*>(xlds);
    #pragma unroll
    for (int pass = 0; pass < 8; ++pass){
      int c = pass * 32 + (t >> 6) * 8;
      float f0 = xp[(size_t)(c+0)*4096], f1 = xp[(size_t)(c+1)*4096];
      float f2 = xp[(size_t)(c+2)*4096], f3 = xp[(size_t)(c+3)*4096];
      float f4 = xp[(size_t)(c+4)*4096], f5 = xp[(size_t)(c+5)*4096];
      float f6 = xp[(size_t)(c+6)*4096], f7 = xp[(size_t)(c+7)*4096];
      uint4 q;
      q.x = (u32)f2bf(f0) | ((u32)f2bf(f1) << 16);
      q.y = (u32)f2bf(f2) | ((u32)f2bf(f3) << 16);
      q.z = (u32)f2bf(f4) | ((u32)f2bf(f5) << 16);
      q.w = (u32)f2bf(f6) | ((u32)f2bf(f7) << 16);
      u32 off = (u32)n * 512 + (((u32)c * 2) ^ (((u32)n & 31) << 4));
      *reinterpret_cast<uint4*>(lbase + off) = q;
    }
  }
  __syncthreads();

  // ---- GEMM: wave w owns d-tiles dt = w*6 .. w*6+5, all 4 n-tiles ----
  f32x4 acc[6][4];
  #pragma unroll
  for (int i = 0; i < 6; ++i)
    #pragma unroll
    for (int nt = 0; nt < 4; ++nt) acc[i][nt] = f32x4{0.f,0.f,0.f,0.f};

  const char* lbase = reinterpret_cast<const char*>(xlds);
  for (int cc = 0; cc < 8; ++cc){
    bf16x8 a[6];
    #pragma unroll
    for (int i = 0; i < 6; ++i)
      a[i] = *reinterpret_cast<const bf16x8*>(wfrag + ((size_t)(cc*24 + w*6 + i) * 64 + lane) * 8);
    bf16x8 bb[4];
    #pragma unroll
    for (int nt = 0; nt < 4; ++nt){
      const u32 row = nt * 16 + j;
      const u32 off = row * 512 + (((u32)(cc * 64 + g * 16)) ^ ((row & 31) << 4));
      bb[nt] = *reinterpret_cast<const bf16x8*>(lbase + off);
    }
    #pragma unroll
    for (int i = 0; i < 6; ++i)
      #pragma unroll
      for (int nt = 0; nt < 4; ++nt)
        acc[i][nt] = __builtin_amdgcn_mfma_f32_16x16x32_bf16(a[i], bb[nt], acc[i][nt], 0, 0, 0);
  }

  // ---- epilogue: bias + convert + store ----
  #pragma unroll
  for (int i = 0; i < 6; ++i){
    const int dt = w * 6 + i;
    const int d0 = dt * 16;
    const int dd = d0 + 4 * g;   // this lane's 4 consecutive d rows
    if (d0 < 64){
      float b0 = bq[dd], b1 = bq[dd+1], b2 = bq[dd+2], b3 = bq[dd+3];
      #pragma unroll
      for (int nt = 0; nt < 4; ++nt){
        const int n = n0 + nt * 16 + j;
        uint2 u;
        u.x = (u32)f2bf(acc[i][nt][0] + b0) | ((u32)f2bf(acc[i][nt][1] + b1) << 16);
        u.y = (u32)f2bf(acc[i][nt][2] + b2) | ((u32)f2bf(acc[i][nt][3] + b3) << 16);
        *reinterpret_cast<uint2*>(qb + ((size_t)b * 4096 + n) * 64 + dd) = u;
      }
    } else if (d0 < 128){
      const int dk = dd - 64;
      float b0 = bk[dk], b1 = bk[dk+1], b2 = bk[dk+2], b3 = bk[dk+3];
      #pragma unroll
      for (int nt = 0; nt < 4; ++nt){
        const int n = n0 + nt * 16 + j;
        uint2 u;
        u.x = (u32)f2bf(acc[i][nt][0] + b0) | ((u32)f2bf(acc[i][nt][1] + b1) << 16);
        u.y = (u32)f2bf(acc[i][nt][2] + b2) | ((u32)f2bf(acc[i][nt][3] + b3) << 16);
        *reinterpret_cast<uint2*>(kb + ((size_t)b * 4096 + n) * 64 + dk) = u;
      }
    } else {
      const int dv = dd - 128;
      float b0 = bv[dv], b1 = bv[dv+1], b2 = bv[dv+2], b3 = bv[dv+3];
      #pragma unroll
      for (int nt = 0; nt < 4; ++nt){
        const int n = n0 + nt * 16 + j;
        u16* vp = vt + (size_t)b * 256 * 4096 + n;
        vp[(size_t)(dv+0) * 4096] = f2bf(acc[i][nt][0] + b0);
        vp[(size_t)(dv+1) * 4096] = f2bf(acc[i][nt][1] + b1);
        vp[(size_t)(dv+2) * 4096] = f2bf(acc[i][nt][2] + b2);
        vp[(size_t)(dv+3) * 4096] = f2bf(acc[i][nt][3] + b3);
      }
    }
  }
}

// ---------------------------------------------------------------------------
// attn_kernel: flash attention. 1 block = 1 (batch, 128 q-rows); 8 waves, each
// wave = 16 q-rows x full Dv=256. KV tiles of 64, double-buffered LDS via
// global_load_lds(16B) with XOR-row-swizzled global sources.
// S computed swapped: S^T = mfma(K, Q)  (lane's column = its q-row).
// O accumulated as O^T[dv][n] -> coalesced f32 stores to out[b][dv][n].
// ---------------------------------------------------------------------------
__launch_bounds__(512, 2)
__global__ void attn_kernel(const u16* __restrict__ qb, const u16* __restrict__ kb,
                            const u16* __restrict__ vt, float* __restrict__ out)
{
  __shared__ u16 kl[2][64 * 64];     // 16 KB  K tile [m][d], rows 128B, swz (m&7)<<4
  __shared__ u16 vl[2][256 * 64];    // 64 KB  V^T tile [dv][m], rows 128B, swz (dv&7)<<4
  __shared__ u16 pl[8][16 * 64];     // 16 KB  per-wave P [n][m], rows 128B, swz (n&7)<<4

  const int b    = blockIdx.x & 7;
  const int qc   = blockIdx.x >> 3;
  const int t    = threadIdx.x, lane = t & 63, w = t >> 6;
  const int g    = lane >> 4, j = lane & 15;

  const u16* Kg = kb + (size_t)b * 4096 * 64;
  const u16* Vg = vt + (size_t)b * 256 * 4096;

  // Q fragments (persistent): B[k=d][j=n] = Q[n][d]
  const u16* Qrow = qb + ((size_t)b * 4096 + qc * 128 + w * 16 + j) * 64;
  const bf16x8 qf0 = *reinterpret_cast<const bf16x8*>(Qrow + 8 * g);
  const bf16x8 qf1 = *reinterpret_cast<const bf16x8*>(Qrow + 32 + 8 * g);

  f32x4 o[16];
  #pragma unroll
  for (int i = 0; i < 16; ++i) o[i] = f32x4{0.f,0.f,0.f,0.f};
  float mrun = -3.0e38f, lrun = 0.f;

  auto stage = [&](int tile, int buf){
    const int m0 = tile * 64;
    {
      const int r = w * 8 + (lane >> 3);                 // K row within tile
      const char* src = reinterpret_cast<const char*>(Kg + (size_t)(m0 + r) * 64)
                        + ((((u32)lane & 7) * 16) ^ ((((u32)r) & 7) << 4));
      char* dst = reinterpret_cast<char*>(&kl[buf][0]) + w * 1024;
      __builtin_amdgcn_global_load_lds((const __attribute__((address_space(1))) void*)src,
                                       (__attribute__((address_space(3))) void*)dst, 16, 0, 0);
    }
    #pragma unroll
    for (int i = 0; i < 4; ++i){
      const int dv = w * 32 + i * 8 + (lane >> 3);       // V^T row (dv)
      const char* src = reinterpret_cast<const char*>(Vg + (size_t)dv * 4096 + m0)
                        + ((((u32)lane & 7) * 16) ^ (((u32)dv & 7) << 4));
      char* dst = reinterpret_cast<char*>(&vl[buf][0]) + (w * 32 + i * 8) * 128;
      __builtin_amdgcn_global_load_lds((const __attribute__((address_space(1))) void*)src,
                                       (__attribute__((address_space(3))) void*)dst, 16, 0, 0);
    }
  };

  stage(0, 0);
  __syncthreads();

  char* pbase = reinterpret_cast<char*>(&pl[w][0]);

  for (int tile = 0; tile < 64; ++tile){
    const int cur = tile & 1;
    if (tile + 1 < 64) stage(tile + 1, cur ^ 1);

    const char* kbase = reinterpret_cast<const char*>(&kl[cur][0]);
    const char* vbase = reinterpret_cast<const char*>(&vl[cur][0]);

    // ---- S^T tile [64 m][16 n]: A = K rows, B = Q rows ----
    f32x4 s[4];
    #pragma unroll
    for (int mt = 0; mt < 4; ++mt){
      const u32 row = mt * 16 + j;
      const u32 sw  = (row & 7) << 4;
      bf16x8 ka0 = *reinterpret_cast<const bf16x8*>(kbase + row * 128 + (((u32)(g * 16)) ^ sw));
      bf16x8 ka1 = *reinterpret_cast<const bf16x8*>(kbase + row * 128 + (((u32)(64 + g * 16)) ^ sw));
      f32x4 z = f32x4{0.f,0.f,0.f,0.f};
      z = __builtin_amdgcn_mfma_f32_16x16x32_bf16(ka0, qf0, z, 0, 0, 0);
      z = __builtin_amdgcn_mfma_f32_16x16x32_bf16(ka1, qf1, z, 0, 0, 0);
      s[mt] = z;   // s[mt][r] = S[m = 16mt+4g+r][n = lane's q-row]
    }

    // ---- online softmax (column n = j is lane-local; reduce over g) ----
    float pmax = s[0][0];
    #pragma unroll
    for (int mt = 0; mt < 4; ++mt)
      #pragma unroll
      for (int r = 0; r < 4; ++r) pmax = fmaxf(pmax, s[mt][r]);
    pmax = fmaxf(pmax, __shfl_xor(pmax, 16));
    pmax = fmaxf(pmax, __shfl_xor(pmax, 32));

    const float mnew  = fmaxf(mrun, pmax);
    const float alpha = exp2f((mrun - mnew) * LOG2E);
    mrun = mnew;

    float psum = 0.f;
    u32 pk[8];
    #pragma unroll
    for (int mt = 0; mt < 4; ++mt){
      float p0 = exp2f((s[mt][0] - mnew) * LOG2E);
      float p1 = exp2f((s[mt][1] - mnew) * LOG2E);
      float p2 = exp2f((s[mt][2] - mnew) * LOG2E);
      float p3 = exp2f((s[mt][3] - mnew) * LOG2E);
      psum += (p0 + p1) + (p2 + p3);
      pk[2*mt]   = (u32)f2bf(p0) | ((u32)f2bf(p1) << 16);
      pk[2*mt+1] = (u32)f2bf(p2) | ((u32)f2bf(p3) << 16);
    }
    psum += __shfl_xor(psum, 16);
    psum += __shfl_xor(psum, 32);
    lrun = lrun * alpha + psum;

    #pragma unroll
    for (int i = 0; i < 16; ++i){
      o[i][0] *= alpha; o[i][1] *= alpha; o[i][2] *= alpha; o[i][3] *= alpha;
    }

    // ---- write P (wave-private, swizzled) ----
    {
      const u32 swp = ((u32)j & 7) << 4;
      #pragma unroll
      for (int mt = 0; mt < 4; ++mt){
        uint2 u; u.x = pk[2*mt]; u.y = pk[2*mt+1];
        *reinterpret_cast<uint2*>(pbase + (u32)j * 128 + (((u32)(mt * 32 + 8 * g)) ^ swp)) = u;
      }
    }

    // ---- PV: O^T[dv][n] += V^T[dv][m] * P^T[m][n] ----
    #pragma unroll
    for (int mc = 0; mc < 2; ++mc){
      const u32 swp = ((u32)j & 7) << 4;
      bf16x8 pf = *reinterpret_cast<const bf16x8*>(pbase + (u32)j * 128 + (((u32)(mc * 64 + 16 * g)) ^ swp));
      #pragma unroll
      for (int dt = 0; dt < 16; ++dt){
        const u32 dv = dt * 16 + j;
        bf16x8 vf = *reinterpret_cast<const bf16x8*>(vbase + dv * 128 + (((u32)(mc * 64 + 16 * g)) ^ ((dv & 7) << 4)));
        o[dt] = __builtin_amdgcn_mfma_f32_16x16x32_bf16(vf, pf, o[dt], 0, 0, 0);
      }
    }

    __syncthreads();
  }

  // ---- epilogue: divide by l, store O^T coalesced ----
  const float rinv = 1.0f / lrun;
  const int n = qc * 128 + w * 16 + j;
  float* ob = out + (size_t)b * 256 * 4096 + n;
  #pragma unroll
  for (int dt = 0; dt < 16; ++dt){
    const int dv0 = dt * 16 + 4 * g;
    #pragma unroll
    for (int r = 0; r < 4; ++r)
      ob[(size_t)(dv0 + r) * 4096] = o[dt][r] * rinv;
  }
}

// ---------------------------------------------------------------------------
extern "C" void kernel_launch(void* const* d_in, const int* in_sizes, int n_in,
                              void* d_out, int out_size, void* d_ws, size_t ws_size,
                              hipStream_t stream)
{
  (void)in_sizes; (void)n_in; (void)out_size; (void)ws_size;
  const float* x  = (const float*)d_in[0];
  const float* wq = (const float*)d_in[1];
  const float* bq = (const float*)d_in[2];
  const float* wk = (const float*)d_in[3];
  const float* bk = (const float*)d_in[4];
  const float* wv = (const float*)d_in[5];
  const float* bv = (const float*)d_in[6];
  float* out = (float*)d_out;

  char* ws = (char*)d_ws;
  u16* qbuf  = (u16*)(ws + 0);            //  4 MB  [8][4096][64]
  u16* kbuf  = (u16*)(ws + 4194304);      //  4 MB  [8][4096][64]
  u16* vbuf  = (u16*)(ws + 8388608);      // 16 MB  [8][256][4096]
  u16* wfrag = (u16*)(ws + 25165824);     // 192 KB

  prep_w<<<dim3(384), dim3(256), 0, stream>>>(wq, wk, wv, wfrag);
  proj_kernel<<<dim3(512), dim3(256), 0, stream>>>(x, bq, bk, bv, wfrag, qbuf, kbuf, vbuf);
  attn_kernel<<<dim3(256), dim3(512), 0, stream>>>(qbuf, kbuf, vbuf, out);
}

// Round 2
// 221.565 us; speedup vs baseline: 1.1899x; 1.1899x over previous
//
#include <hip/hip_runtime.h>

typedef __bf16 bf16x8 __attribute__((ext_vector_type(8)));
typedef float f32x4 __attribute__((ext_vector_type(4)));
typedef unsigned int u32;
typedef u32 u32x4v __attribute__((ext_vector_type(4)));
typedef unsigned short u16;

#define LOG2E 1.44269504088896f

__device__ __forceinline__ u16 f2bf(float f){
  u32 b = __builtin_bit_cast(u32, f);
  b += 0x7FFFu + ((b >> 16) & 1u);
  return (u16)(b >> 16);
}

// ---------------------------------------------------------------------------
// prep_w: build fragment-ordered bf16 weights.
// flat idx = ((cc*24+dt)*64 + lane)*8 + e  ->  W[d = dt*16+(lane&15)][c = cc*32+(lane>>4)*8+e]
// rows 0..63 = w_q, 64..127 = w_k, 128..383 = w_v
// ---------------------------------------------------------------------------
__global__ void prep_w(const float* __restrict__ wq, const float* __restrict__ wk,
                       const float* __restrict__ wv, u16* __restrict__ wfrag){
  int idx  = blockIdx.x * 256 + threadIdx.x;     // < 98304
  int e    = idx & 7;
  int lane = (idx >> 3) & 63;
  int f    = idx >> 9;                           // 0..191
  int cc = f / 24, dt = f % 24;
  int d = dt * 16 + (lane & 15);
  int c = cc * 32 + (lane >> 4) * 8 + e;
  float v;
  if (d < 64)       v = wq[d * 256 + c];
  else if (d < 128) v = wk[(d - 64) * 256 + c];
  else              v = wv[(d - 128) * 256 + c];
  wfrag[idx] = f2bf(v);
}

// ---------------------------------------------------------------------------
// proj_kernel: Out[d][n] = sum_c W[d][c] x[b][c][n] + bias
//   Q written PRE-SCALED by log2(e), as [B][N][64] bf16 (d contiguous)
//   K written as [B][N][64] bf16
//   V written as [B][256][N] bf16 with each 64-column tile PERMUTED by pi^-1
//     (s = m5 m3 m2 m4 m1 m0) so attn's PV B-fragment needs no P shuffle.
// ---------------------------------------------------------------------------
__launch_bounds__(256, 2)
__global__ void proj_kernel(const float* __restrict__ x,
                            const float* __restrict__ bq, const float* __restrict__ bk,
                            const float* __restrict__ bv,
                            const u16* __restrict__ wfrag,
                            u16* __restrict__ qb, u16* __restrict__ kb, u16* __restrict__ vt)
{
  __shared__ u16 xlds[64 * 256];     // 32 KB
  const int b    = blockIdx.x & 7;
  const int n0   = (blockIdx.x >> 3) * 64;
  const int t    = threadIdx.x;
  const int lane = t & 63;
  const int w    = t >> 6;
  const int g    = lane >> 4, j = lane & 15;

  // ---- stage: transpose-convert x[b][:, n0..n0+63] into xlds[n][c] ----
  {
    const int n = t & 63;
    const float* xp = x + ((size_t)b * 256) * 4096 + n0 + n;
    char* lbase = reinterpret_cast<char*>(xlds);
    #pragma unroll
    for (int pass = 0; pass < 8; ++pass){
      int c = pass * 32 + (t >> 6) * 8;
      float f0 = xp[(size_t)(c+0)*4096], f1 = xp[(size_t)(c+1)*4096];
      float f2 = xp[(size_t)(c+2)*4096], f3 = xp[(size_t)(c+3)*4096];
      float f4 = xp[(size_t)(c+4)*4096], f5 = xp[(size_t)(c+5)*4096];
      float f6 = xp[(size_t)(c+6)*4096], f7 = xp[(size_t)(c+7)*4096];
      uint4 q;
      q.x = (u32)f2bf(f0) | ((u32)f2bf(f1) << 16);
      q.y = (u32)f2bf(f2) | ((u32)f2bf(f3) << 16);
      q.z = (u32)f2bf(f4) | ((u32)f2bf(f5) << 16);
      q.w = (u32)f2bf(f6) | ((u32)f2bf(f7) << 16);
      u32 off = (u32)n * 512 + (((u32)c * 2) ^ (((u32)n & 31) << 4));
      *reinterpret_cast<uint4*>(lbase + off) = q;
    }
  }
  __syncthreads();

  // ---- GEMM: wave w owns d-tiles dt = w*6 .. w*6+5, all 4 n-tiles ----
  f32x4 acc[6][4];
  #pragma unroll
  for (int i = 0; i < 6; ++i)
    #pragma unroll
    for (int nt = 0; nt < 4; ++nt) acc[i][nt] = f32x4{0.f,0.f,0.f,0.f};

  const char* lbase = reinterpret_cast<const char*>(xlds);
  for (int cc = 0; cc < 8; ++cc){
    bf16x8 a[6];
    #pragma unroll
    for (int i = 0; i < 6; ++i)
      a[i] = *reinterpret_cast<const bf16x8*>(wfrag + ((size_t)(cc*24 + w*6 + i) * 64 + lane) * 8);
    bf16x8 bb[4];
    #pragma unroll
    for (int nt = 0; nt < 4; ++nt){
      const u32 row = nt * 16 + j;
      const u32 off = row * 512 + (((u32)(cc * 64 + g * 16)) ^ ((row & 31) << 4));
      bb[nt] = *reinterpret_cast<const bf16x8*>(lbase + off);
    }
    #pragma unroll
    for (int i = 0; i < 6; ++i)
      #pragma unroll
      for (int nt = 0; nt < 4; ++nt)
        acc[i][nt] = __builtin_amdgcn_mfma_f32_16x16x32_bf16(a[i], bb[nt], acc[i][nt], 0, 0, 0);
  }

  // ---- epilogue: bias + convert + store ----
  #pragma unroll
  for (int i = 0; i < 6; ++i){
    const int dt = w * 6 + i;
    const int d0 = dt * 16;
    const int dd = d0 + 4 * g;   // this lane's 4 consecutive d rows
    if (d0 < 64){
      float b0 = bq[dd], b1 = bq[dd+1], b2 = bq[dd+2], b3 = bq[dd+3];
      #pragma unroll
      for (int nt = 0; nt < 4; ++nt){
        const int n = n0 + nt * 16 + j;
        uint2 u;
        u.x = (u32)f2bf((acc[i][nt][0] + b0) * LOG2E) | ((u32)f2bf((acc[i][nt][1] + b1) * LOG2E) << 16);
        u.y = (u32)f2bf((acc[i][nt][2] + b2) * LOG2E) | ((u32)f2bf((acc[i][nt][3] + b3) * LOG2E) << 16);
        *reinterpret_cast<uint2*>(qb + ((size_t)b * 4096 + n) * 64 + dd) = u;
      }
    } else if (d0 < 128){
      const int dk = dd - 64;
      float b0 = bk[dk], b1 = bk[dk+1], b2 = bk[dk+2], b3 = bk[dk+3];
      #pragma unroll
      for (int nt = 0; nt < 4; ++nt){
        const int n = n0 + nt * 16 + j;
        uint2 u;
        u.x = (u32)f2bf(acc[i][nt][0] + b0) | ((u32)f2bf(acc[i][nt][1] + b1) << 16);
        u.y = (u32)f2bf(acc[i][nt][2] + b2) | ((u32)f2bf(acc[i][nt][3] + b3) << 16);
        *reinterpret_cast<uint2*>(kb + ((size_t)b * 4096 + n) * 64 + dk) = u;
      }
    } else {
      const int dv = dd - 128;
      float b0 = bv[dv], b1 = bv[dv+1], b2 = bv[dv+2], b3 = bv[dv+3];
      #pragma unroll
      for (int nt = 0; nt < 4; ++nt){
        // permuted column: s = m5 m3 m2 m4 m1 m0  (m = nt*16 + j)
        const int scol = ((nt & 2) << 4) | ((j & 12) << 1) | ((nt & 1) << 2) | (j & 3);
        const int n = n0 + scol;
        u16* vp = vt + (size_t)b * 256 * 4096 + n;
        vp[(size_t)(dv+0) * 4096] = f2bf(acc[i][nt][0] + b0);
        vp[(size_t)(dv+1) * 4096] = f2bf(acc[i][nt][1] + b1);
        vp[(size_t)(dv+2) * 4096] = f2bf(acc[i][nt][2] + b2);
        vp[(size_t)(dv+3) * 4096] = f2bf(acc[i][nt][3] + b3);
      }
    }
  }
}

// ---------------------------------------------------------------------------
// attn_kernel v2: 512 blocks x 4 waves (64 q-rows/block, 16 per wave).
// LDS = 80 KB -> 2 blocks/CU (two independent barrier domains).
// S^T = mfma(K, Q_prescaled); softmax column-local; P bit-cast DIRECTLY into
// the PV B-fragment (V stored m-permuted, no P-LDS). Defer-max THR=8.
// O accumulated as O^T[dv][n] -> coalesced f32 stores.
// ---------------------------------------------------------------------------
__launch_bounds__(256, 2)
__global__ void attn_kernel(const u16* __restrict__ qb, const u16* __restrict__ kb,
                            const u16* __restrict__ vt, float* __restrict__ out)
{
  __shared__ u16 kl[2][64 * 64];     // 16 KB  K tile [m][d], rows 128B, swz (m&7)<<4
  __shared__ u16 vl[2][256 * 64];    // 64 KB  V^T tile [dv][s], rows 128B, swz (dv&7)<<4

  const int b    = blockIdx.x & 7;
  const int qc   = blockIdx.x >> 3;            // 0..63
  const int t    = threadIdx.x, lane = t & 63, w = t >> 6;   // w: 0..3
  const int g    = lane >> 4, j = lane & 15;

  const u16* Kg = kb + (size_t)b * 4096 * 64;
  const u16* Vg = vt + (size_t)b * 256 * 4096;

  // Q fragments (persistent, pre-scaled by log2e): B[k=d][col=n]
  const u16* Qrow = qb + ((size_t)b * 4096 + qc * 64 + w * 16 + j) * 64;
  const bf16x8 qf0 = *reinterpret_cast<const bf16x8*>(Qrow + 8 * g);
  const bf16x8 qf1 = *reinterpret_cast<const bf16x8*>(Qrow + 32 + 8 * g);

  f32x4 o[16];
  #pragma unroll
  for (int i = 0; i < 16; ++i) o[i] = f32x4{0.f,0.f,0.f,0.f};
  float mrun = -1.0e30f, lrun = 0.f;

  auto stage = [&](int tile, int buf){
    const int m0 = tile * 64;
    #pragma unroll
    for (int i = 0; i < 2; ++i){             // K tile: 64 rows x 128B
      const int r = i * 32 + w * 8 + (lane >> 3);
      const char* src = reinterpret_cast<const char*>(Kg + (size_t)(m0 + r) * 64)
                        + ((((u32)lane & 7) * 16) ^ ((((u32)r) & 7) << 4));
      char* dst = reinterpret_cast<char*>(&kl[buf][0]) + i * 4096 + w * 1024;
      __builtin_amdgcn_global_load_lds((const __attribute__((address_space(1))) void*)src,
                                       (__attribute__((address_space(3))) void*)dst, 16, 0, 0);
    }
    #pragma unroll
    for (int i = 0; i < 8; ++i){             // V^T tile: 256 rows x 128B
      const int dv = i * 32 + w * 8 + (lane >> 3);
      const char* src = reinterpret_cast<const char*>(Vg + (size_t)dv * 4096 + m0)
                        + ((((u32)lane & 7) * 16) ^ (((u32)dv & 7) << 4));
      char* dst = reinterpret_cast<char*>(&vl[buf][0]) + i * 4096 + w * 1024;
      __builtin_amdgcn_global_load_lds((const __attribute__((address_space(1))) void*)src,
                                       (__attribute__((address_space(3))) void*)dst, 16, 0, 0);
    }
  };

  stage(0, 0);
  __syncthreads();

  const u32 vsw = ((u32)j & 7) << 4;   // V read swizzle (dv&7 == j&7, loop-invariant)

  for (int tile = 0; tile < 64; ++tile){
    const int cur = tile & 1;
    if (tile + 1 < 64) stage(tile + 1, cur ^ 1);

    const char* kbase = reinterpret_cast<const char*>(&kl[cur][0]);
    const char* vbase = reinterpret_cast<const char*>(&vl[cur][0]);

    // ---- S^T tile [64 m][16 n]: A = K rows, B = Q rows (log2 domain) ----
    f32x4 s[4];
    __builtin_amdgcn_s_setprio(1);
    #pragma unroll
    for (int mt = 0; mt < 4; ++mt){
      const u32 row = mt * 16 + j;
      const u32 sw  = (row & 7) << 4;
      bf16x8 ka0 = *reinterpret_cast<const bf16x8*>(kbase + row * 128 + (((u32)(g * 16)) ^ sw));
      bf16x8 ka1 = *reinterpret_cast<const bf16x8*>(kbase + row * 128 + (((u32)(64 + g * 16)) ^ sw));
      f32x4 z = f32x4{0.f,0.f,0.f,0.f};
      z = __builtin_amdgcn_mfma_f32_16x16x32_bf16(ka0, qf0, z, 0, 0, 0);
      z = __builtin_amdgcn_mfma_f32_16x16x32_bf16(ka1, qf1, z, 0, 0, 0);
      s[mt] = z;   // s[mt][r] = S2[m = 16mt+4g+r][n = this lane's q-row], log2 domain
    }
    __builtin_amdgcn_s_setprio(0);

    // ---- online softmax (base-2; column n = j lane-local; reduce over g) ----
    float pmax = s[0][0];
    #pragma unroll
    for (int mt = 0; mt < 4; ++mt)
      #pragma unroll
      for (int r = 0; r < 4; ++r) pmax = fmaxf(pmax, s[mt][r]);
    pmax = fmaxf(pmax, __shfl_xor(pmax, 16));
    pmax = fmaxf(pmax, __shfl_xor(pmax, 32));

    // defer-max: rescale only when some row's max grew past mrun + 8
    if (__any(pmax > mrun + 8.0f)){
      const float mnew  = fmaxf(mrun, pmax);
      const float alpha = __builtin_amdgcn_exp2f(mrun - mnew);
      mrun = mnew;
      lrun *= alpha;
      #pragma unroll
      for (int i = 0; i < 16; ++i){
        o[i][0] *= alpha; o[i][1] *= alpha; o[i][2] *= alpha; o[i][3] *= alpha;
      }
    }

    float psum = 0.f;
    u32 pk[8];
    #pragma unroll
    for (int mt = 0; mt < 4; ++mt){
      float p0 = __builtin_amdgcn_exp2f(s[mt][0] - mrun);
      float p1 = __builtin_amdgcn_exp2f(s[mt][1] - mrun);
      float p2 = __builtin_amdgcn_exp2f(s[mt][2] - mrun);
      float p3 = __builtin_amdgcn_exp2f(s[mt][3] - mrun);
      psum += (p0 + p1) + (p2 + p3);
      pk[2*mt]   = (u32)f2bf(p0) | ((u32)f2bf(p1) << 16);
      pk[2*mt+1] = (u32)f2bf(p2) | ((u32)f2bf(p3) << 16);
    }
    psum += __shfl_xor(psum, 16);
    psum += __shfl_xor(psum, 32);
    lrun += psum;

    // ---- PV: O^T[dv][n] += V^T[dv][s] * P[s][n] ; pk IS the B-fragment ----
    __builtin_amdgcn_s_setprio(1);
    #pragma unroll
    for (int mc = 0; mc < 2; ++mc){
      u32x4v pw = { pk[4*mc+0], pk[4*mc+1], pk[4*mc+2], pk[4*mc+3] };
      bf16x8 pf = __builtin_bit_cast(bf16x8, pw);
      #pragma unroll
      for (int dt = 0; dt < 16; ++dt){
        const u32 dv = dt * 16 + j;
        bf16x8 vf = *reinterpret_cast<const bf16x8*>(vbase + dv * 128 + (((u32)(mc * 64 + 16 * g)) ^ vsw));
        o[dt] = __builtin_amdgcn_mfma_f32_16x16x32_bf16(vf, pf, o[dt], 0, 0, 0);
      }
    }
    __builtin_amdgcn_s_setprio(0);

    __syncthreads();
  }

  // ---- epilogue: divide by l, store O^T coalesced ----
  const float rinv = 1.0f / lrun;
  const int n = qc * 64 + w * 16 + j;
  float* ob = out + (size_t)b * 256 * 4096 + n;
  #pragma unroll
  for (int dt = 0; dt < 16; ++dt){
    const int dv0 = dt * 16 + 4 * g;
    #pragma unroll
    for (int r = 0; r < 4; ++r)
      ob[(size_t)(dv0 + r) * 4096] = o[dt][r] * rinv;
  }
}

// ---------------------------------------------------------------------------
extern "C" void kernel_launch(void* const* d_in, const int* in_sizes, int n_in,
                              void* d_out, int out_size, void* d_ws, size_t ws_size,
                              hipStream_t stream)
{
  (void)in_sizes; (void)n_in; (void)out_size; (void)ws_size;
  const float* x  = (const float*)d_in[0];
  const float* wq = (const float*)d_in[1];
  const float* bq = (const float*)d_in[2];
  const float* wk = (const float*)d_in[3];
  const float* bk = (const float*)d_in[4];
  const float* wv = (const float*)d_in[5];
  const float* bv = (const float*)d_in[6];
  float* out = (float*)d_out;

  char* ws = (char*)d_ws;
  u16* qbuf  = (u16*)(ws + 0);            //  4 MB  [8][4096][64]  (pre-scaled by log2e)
  u16* kbuf  = (u16*)(ws + 4194304);      //  4 MB  [8][4096][64]
  u16* vbuf  = (u16*)(ws + 8388608);      // 16 MB  [8][256][4096] (m-permuted per 64-tile)
  u16* wfrag = (u16*)(ws + 25165824);     // 192 KB

  prep_w<<<dim3(384), dim3(256), 0, stream>>>(wq, wk, wv, wfrag);
  proj_kernel<<<dim3(512), dim3(256), 0, stream>>>(x, bq, bk, bv, wfrag, qbuf, kbuf, vbuf);
  attn_kernel<<<dim3(512), dim3(256), 0, stream>>>(qbuf, kbuf, vbuf, out);
}